// Round 3
// baseline (110.437 us; speedup 1.0000x reference)
//
#include <hip/hip_runtime.h>

// Soft-sphere multi-species: energy + analytic forces. N=4096, S=8.
// O(N^2) tiled pair kernel. Grid: (N/TI) i-tiles x (N/TJ) j-chunks.
// Each thread owns particle i; j-chunk staged in LDS as float4 (xyz+species).
// Diagonal-cell fast path (uniform branch): per-axis minimum image.
// Per-pair tables {1/sig, alpha-1, eps/alpha, eps/sig} precomputed in LDS.
// f^(alpha-1) via hardware v_exp_f32/v_log_f32 (__builtin_amdgcn_*): f in (0,1],
// rel err ~2^-21 * alpha — absmax stays ~1e-3, threshold is 5.28.
//
// R1 post-mortem: the two 256 MiB / 39.3 us fills are HARNESS poison
// (counted in dur_us, not controllable). Kernel itself ~12-15 us vs a
// ~3.4 us VALU floor -> latency-stalled at 4 waves/SIMD (4096 waves total).
//
// R2: TJ 64 -> 32. Doubles wave count (8192 waves = 8/SIMD, 8 blocks/CU)
// to hide the dep-chain + LDS latency. Cost: force atomics double
// (786K -> 1.57M) — predicted +1 us, dominated by latency-hiding gain.
// R3: R2 bench was an infra failure (container acquisition), not a kernel
// signal — resubmitting the same experiment for measurement.

#define TI 256
#define TJ 32
#define CUT2 2.25f  // CUTOFF=1.5 squared

__device__ __forceinline__ float fast_pow(float f, float e) {
    // f > 0 guaranteed. 2^(e * log2(f)) on the hardware transcendental pipe.
    return __builtin_amdgcn_exp2f(e * __builtin_amdgcn_logf(f));
}

__global__ __launch_bounds__(TI) void soft_sphere_kernel(
    const float* __restrict__ pos,
    const float* __restrict__ cell,
    const float* __restrict__ sigm,
    const float* __restrict__ epsm,
    const float* __restrict__ alpm,
    const int*   __restrict__ spec,
    float* __restrict__ out,   // out[0]=energy, out[1..3N]=forces
    int n)
{
    __shared__ float4 sh_pos[TJ];   // j positions + species bits in .w
    __shared__ float4 sh_tab[64];   // {inv_sig, alpha-1, eps/alpha, eps/sig}
    __shared__ float  sh_e[TI / 64];

    const int tid = threadIdx.x;
    const int j0  = blockIdx.y * TJ;

    if (tid < 64) {
        // Species-pair coefficient tables (8x8 = 64 entries).
        float sg = sigm[tid], ep = epsm[tid], al = alpm[tid];
        float inv_sg = 1.0f / sg;
        sh_tab[tid] = make_float4(inv_sg, al - 1.0f, ep / al, ep * inv_sg);
        // j-chunk staging (TJ <= 64).
        if (tid < TJ) {
            int j = j0 + tid;
            sh_pos[tid] = make_float4(pos[3 * j + 0], pos[3 * j + 1],
                                      pos[3 * j + 2], __int_as_float(spec[j]));
        }
    }

    // Cell (uniform -> SGPRs).
    const float m00 = cell[0], m01 = cell[1], m02 = cell[2];
    const float m10 = cell[3], m11 = cell[4], m12 = cell[5];
    const float m20 = cell[6], m21 = cell[7], m22 = cell[8];
    const bool diag = (m01 == 0.0f) & (m02 == 0.0f) & (m10 == 0.0f) &
                      (m12 == 0.0f) & (m20 == 0.0f) & (m21 == 0.0f);

    const int   i   = blockIdx.x * TI + tid;
    const float px  = pos[3 * i + 0];
    const float py  = pos[3 * i + 1];
    const float pz  = pos[3 * i + 2];
    const int   si8 = spec[i] << 3;

    __syncthreads();

    float e_acc = 0.0f, fxa = 0.0f, fya = 0.0f, fza = 0.0f;

    if (diag) {
        // Orthorhombic fast path: per-axis minimum image.
        const float iLx = 1.0f / m00, iLy = 1.0f / m11, iLz = 1.0f / m22;
#pragma unroll 4
        for (int t = 0; t < TJ; ++t) {
            float4 pj = sh_pos[t];
            float dx = pj.x - px;
            float dy = pj.y - py;
            float dz = pj.z - pz;
            dx = fmaf(-rintf(dx * iLx), m00, dx);
            dy = fmaf(-rintf(dy * iLy), m11, dy);
            dz = fmaf(-rintf(dz * iLz), m22, dz);
            float r2 = fmaf(dx, dx, fmaf(dy, dy, dz * dz));
            if (r2 < CUT2 && (j0 + t) != i) {
                float4 tab = sh_tab[si8 + __float_as_int(pj.w)];
                float rinv = rsqrtf(r2);
                float r    = r2 * rinv;
                float f    = fmaf(-r, tab.x, 1.0f);   // 1 - r/sig
                if (f > 0.0f) {
                    float p = fast_pow(f, tab.y);        // f^(alpha-1)
                    e_acc = fmaf(tab.z * p, f, e_acc);   // eps/alpha * f^alpha
                    float c = tab.w * p * rinv;          // eps/(sig*r) * f^(a-1)
                    fxa = fmaf(-c, dx, fxa);
                    fya = fmaf(-c, dy, fya);
                    fza = fmaf(-c, dz, fza);
                }
            }
        }
    } else {
        // General triclinic path (never taken for this input, kept for correctness).
        const float det = m00 * (m11 * m22 - m12 * m21)
                        - m01 * (m10 * m22 - m12 * m20)
                        + m02 * (m10 * m21 - m11 * m20);
        const float rdet = 1.0f / det;
        const float i00 = (m11 * m22 - m12 * m21) * rdet;
        const float i01 = (m02 * m21 - m01 * m22) * rdet;
        const float i02 = (m01 * m12 - m02 * m11) * rdet;
        const float i10 = (m12 * m20 - m10 * m22) * rdet;
        const float i11 = (m00 * m22 - m02 * m20) * rdet;
        const float i12 = (m02 * m10 - m00 * m12) * rdet;
        const float i20 = (m10 * m21 - m11 * m20) * rdet;
        const float i21 = (m01 * m20 - m00 * m21) * rdet;
        const float i22 = (m00 * m11 - m01 * m10) * rdet;
#pragma unroll 2
        for (int t = 0; t < TJ; ++t) {
            float4 pj = sh_pos[t];
            float dx = pj.x - px, dy = pj.y - py, dz = pj.z - pz;
            float fx = dx * i00 + dy * i10 + dz * i20;
            float fy = dx * i01 + dy * i11 + dz * i21;
            float fz = dx * i02 + dy * i12 + dz * i22;
            fx -= rintf(fx); fy -= rintf(fy); fz -= rintf(fz);
            float ddx = fx * m00 + fy * m10 + fz * m20;
            float ddy = fx * m01 + fy * m11 + fz * m21;
            float ddz = fx * m02 + fy * m12 + fz * m22;
            float r2 = fmaf(ddx, ddx, fmaf(ddy, ddy, ddz * ddz));
            if (r2 < CUT2 && (j0 + t) != i) {
                float4 tab = sh_tab[si8 + __float_as_int(pj.w)];
                float rinv = rsqrtf(r2);
                float r    = r2 * rinv;
                float f    = fmaf(-r, tab.x, 1.0f);
                if (f > 0.0f) {
                    float p = fast_pow(f, tab.y);
                    e_acc = fmaf(tab.z * p, f, e_acc);
                    float c = tab.w * p * rinv;
                    fxa = fmaf(-c, ddx, fxa);
                    fya = fmaf(-c, ddy, fya);
                    fza = fmaf(-c, ddz, fza);
                }
            }
        }
    }

    // Merge partial forces across j-chunk blocks.
    atomicAdd(&out[1 + 3 * i + 0], fxa);
    atomicAdd(&out[1 + 3 * i + 1], fya);
    atomicAdd(&out[1 + 3 * i + 2], fza);

    // Energy: wave shuffle reduce -> LDS across waves -> one atomic per block.
    for (int off = 32; off > 0; off >>= 1)
        e_acc += __shfl_down(e_acc, off, 64);
    if ((tid & 63) == 0) sh_e[tid >> 6] = e_acc;
    __syncthreads();
    if (tid == 0) {
        float tot = 0.0f;
        for (int w = 0; w < TI / 64; ++w) tot += sh_e[w];
        atomicAdd(&out[0], 0.5f * tot);  // ordered pairs counted twice
    }
}

extern "C" void kernel_launch(void* const* d_in, const int* in_sizes, int n_in,
                              void* d_out, int out_size, void* d_ws, size_t ws_size,
                              hipStream_t stream) {
    const float* pos  = (const float*)d_in[0];
    const float* cell = (const float*)d_in[1];
    const float* sigm = (const float*)d_in[2];
    const float* epsm = (const float*)d_in[3];
    const float* alpm = (const float*)d_in[4];
    const int*   spec = (const int*)d_in[5];
    float* out = (float*)d_out;
    const int n = in_sizes[5];  // species array length = N

    // Zero only the logical output region (energy + 3N forces).
    size_t logical = (size_t)(1 + 3 * n);
    if ((size_t)out_size < logical) logical = (size_t)out_size;
    (void)hipMemsetAsync(out, 0, logical * sizeof(float), stream);

    dim3 grid(n / TI, (n + TJ - 1) / TJ);
    soft_sphere_kernel<<<grid, TI, 0, stream>>>(pos, cell, sigm, epsm, alpm,
                                                spec, out, n);
}

// Round 4
// 92.786 us; speedup vs baseline: 1.1902x; 1.1902x over previous
//
#include <hip/hip_runtime.h>

// Soft-sphere multi-species: energy + analytic forces. N=4096, S=8.
// O(N^2) tiled pair kernel. Grid: (N/TI) i-tiles x (N/TJ) j-chunks.
// Each thread owns particle i; j-chunk staged in LDS as float4 (xyz+species).
// Diagonal-cell fast path (uniform branch): per-axis minimum image.
// Per-pair tables {1/sig, alpha-1, eps/alpha, eps/sig} precomputed in LDS.
// f^(alpha-1) via hardware v_exp_f32/v_log_f32: f in (0,1].
//
// R3 post-mortem (the key counter evidence): WRITE_SIZE = 18.75 MB per
// dispatch at 440 GB/s == the kernel's 44 us. Force atomicAdds are
// device-scope RMWs at the memory-side coherence point (per-XCD L2s are
// not cross-coherent) -> the kernel is ATOMIC-TRAFFIC-bound, not
// VALU/latency-bound (VALUBusy 19%, HBM 5.5%). TJ 64->32 doubled atomic
// count, hence the +15 us regression.
//
// R4: privatize force accumulation. Pair block (bx,by) plain-stores its
// partial forces as float4 to ws[by*N + i] (coalesced, L2-absorbable,
// no RMW). A second tiny kernel sums the N/TJ=64 chunk partials per
// component and plain-stores out[1..3N]. Zero force atomics remain;
// only 1024 energy atomics (negligible). TJ reverted to 64.
// Fallback to the atomic path if ws_size < 64*N*16 B (4.2 MB).

#define TI 256
#define TJ 64
#define CUT2 2.25f  // CUTOFF=1.5 squared

__device__ __forceinline__ float fast_pow(float f, float e) {
    // f > 0 guaranteed. 2^(e * log2(f)) on the hardware transcendental pipe.
    return __builtin_amdgcn_exp2f(e * __builtin_amdgcn_logf(f));
}

__global__ __launch_bounds__(TI) void soft_sphere_kernel(
    const float* __restrict__ pos,
    const float* __restrict__ cell,
    const float* __restrict__ sigm,
    const float* __restrict__ epsm,
    const float* __restrict__ alpm,
    const int*   __restrict__ spec,
    float*  __restrict__ out,   // out[0]=energy, out[1..3N]=forces
    float4* __restrict__ ws,    // partial forces [nchunks][N]; null -> atomic path
    int n)
{
    __shared__ float4 sh_pos[TJ];   // j positions + species bits in .w
    __shared__ float4 sh_tab[64];   // {inv_sig, alpha-1, eps/alpha, eps/sig}
    __shared__ float  sh_e[TI / 64];

    const int tid = threadIdx.x;
    const int j0  = blockIdx.y * TJ;

    if (tid < 64) {
        // Species-pair coefficient tables (8x8 = 64 entries).
        float sg = sigm[tid], ep = epsm[tid], al = alpm[tid];
        float inv_sg = 1.0f / sg;
        sh_tab[tid] = make_float4(inv_sg, al - 1.0f, ep / al, ep * inv_sg);
        // j-chunk staging (TJ == 64).
        int j = j0 + tid;
        sh_pos[tid] = make_float4(pos[3 * j + 0], pos[3 * j + 1],
                                  pos[3 * j + 2], __int_as_float(spec[j]));
    }

    // Cell (uniform -> SGPRs).
    const float m00 = cell[0], m01 = cell[1], m02 = cell[2];
    const float m10 = cell[3], m11 = cell[4], m12 = cell[5];
    const float m20 = cell[6], m21 = cell[7], m22 = cell[8];
    const bool diag = (m01 == 0.0f) & (m02 == 0.0f) & (m10 == 0.0f) &
                      (m12 == 0.0f) & (m20 == 0.0f) & (m21 == 0.0f);

    const int   i   = blockIdx.x * TI + tid;
    const float px  = pos[3 * i + 0];
    const float py  = pos[3 * i + 1];
    const float pz  = pos[3 * i + 2];
    const int   si8 = spec[i] << 3;

    __syncthreads();

    float e_acc = 0.0f, fxa = 0.0f, fya = 0.0f, fza = 0.0f;

    if (diag) {
        // Orthorhombic fast path: per-axis minimum image.
        const float iLx = 1.0f / m00, iLy = 1.0f / m11, iLz = 1.0f / m22;
#pragma unroll 4
        for (int t = 0; t < TJ; ++t) {
            float4 pj = sh_pos[t];
            float dx = pj.x - px;
            float dy = pj.y - py;
            float dz = pj.z - pz;
            dx = fmaf(-rintf(dx * iLx), m00, dx);
            dy = fmaf(-rintf(dy * iLy), m11, dy);
            dz = fmaf(-rintf(dz * iLz), m22, dz);
            float r2 = fmaf(dx, dx, fmaf(dy, dy, dz * dz));
            if (r2 < CUT2 && (j0 + t) != i) {
                float4 tab = sh_tab[si8 + __float_as_int(pj.w)];
                float rinv = rsqrtf(r2);
                float r    = r2 * rinv;
                float f    = fmaf(-r, tab.x, 1.0f);   // 1 - r/sig
                if (f > 0.0f) {
                    float p = fast_pow(f, tab.y);        // f^(alpha-1)
                    e_acc = fmaf(tab.z * p, f, e_acc);   // eps/alpha * f^alpha
                    float c = tab.w * p * rinv;          // eps/(sig*r) * f^(a-1)
                    fxa = fmaf(-c, dx, fxa);
                    fya = fmaf(-c, dy, fya);
                    fza = fmaf(-c, dz, fza);
                }
            }
        }
    } else {
        // General triclinic path (never taken for this input, kept for correctness).
        const float det = m00 * (m11 * m22 - m12 * m21)
                        - m01 * (m10 * m22 - m12 * m20)
                        + m02 * (m10 * m21 - m11 * m20);
        const float rdet = 1.0f / det;
        const float i00 = (m11 * m22 - m12 * m21) * rdet;
        const float i01 = (m02 * m21 - m01 * m22) * rdet;
        const float i02 = (m01 * m12 - m02 * m11) * rdet;
        const float i10 = (m12 * m20 - m10 * m22) * rdet;
        const float i11 = (m00 * m22 - m02 * m20) * rdet;
        const float i12 = (m02 * m10 - m00 * m12) * rdet;
        const float i20 = (m10 * m21 - m11 * m20) * rdet;
        const float i21 = (m01 * m20 - m00 * m21) * rdet;
        const float i22 = (m00 * m11 - m01 * m10) * rdet;
#pragma unroll 2
        for (int t = 0; t < TJ; ++t) {
            float4 pj = sh_pos[t];
            float dx = pj.x - px, dy = pj.y - py, dz = pj.z - pz;
            float fx = dx * i00 + dy * i10 + dz * i20;
            float fy = dx * i01 + dy * i11 + dz * i21;
            float fz = dx * i02 + dy * i12 + dz * i22;
            fx -= rintf(fx); fy -= rintf(fy); fz -= rintf(fz);
            float ddx = fx * m00 + fy * m10 + fz * m20;
            float ddy = fx * m01 + fy * m11 + fz * m21;
            float ddz = fx * m02 + fy * m12 + fz * m22;
            float r2 = fmaf(ddx, ddx, fmaf(ddy, ddy, ddz * ddz));
            if (r2 < CUT2 && (j0 + t) != i) {
                float4 tab = sh_tab[si8 + __float_as_int(pj.w)];
                float rinv = rsqrtf(r2);
                float r    = r2 * rinv;
                float f    = fmaf(-r, tab.x, 1.0f);
                if (f > 0.0f) {
                    float p = fast_pow(f, tab.y);
                    e_acc = fmaf(tab.z * p, f, e_acc);
                    float c = tab.w * p * rinv;
                    fxa = fmaf(-c, ddx, fxa);
                    fya = fmaf(-c, ddy, fya);
                    fza = fmaf(-c, ddz, fza);
                }
            }
        }
    }

    // Force output: privatized plain store (no RMW traffic) when ws given.
    if (ws != nullptr) {
        ws[(size_t)blockIdx.y * n + i] = make_float4(fxa, fya, fza, 0.0f);
    } else {
        atomicAdd(&out[1 + 3 * i + 0], fxa);
        atomicAdd(&out[1 + 3 * i + 1], fya);
        atomicAdd(&out[1 + 3 * i + 2], fza);
    }

    // Energy: wave shuffle reduce -> LDS across waves -> one atomic per block.
    for (int off = 32; off > 0; off >>= 1)
        e_acc += __shfl_down(e_acc, off, 64);
    if ((tid & 63) == 0) sh_e[tid >> 6] = e_acc;
    __syncthreads();
    if (tid == 0) {
        float tot = 0.0f;
        for (int w = 0; w < TI / 64; ++w) tot += sh_e[w];
        atomicAdd(&out[0], 0.5f * tot);  // ordered pairs counted twice
    }
}

// Sum the per-chunk partial forces. One thread per padded component
// (4 per particle; the .w pad is summed but discarded). Reads are
// lane-consecutive -> fully coalesced 256B/wave per chunk row.
__global__ __launch_bounds__(256) void reduce_forces(
    const float* __restrict__ ws,   // [nchunks][n][4]
    float* __restrict__ out,        // out[1..3n] forces
    int n, int nchunks)
{
    const int idx = blockIdx.x * 256 + threadIdx.x;   // [0, 4n)
    const int total = 4 * n;
    if (idx >= total) return;
    float s = 0.0f;
#pragma unroll 8
    for (int c = 0; c < nchunks; ++c)
        s += ws[(size_t)c * total + idx];
    const int i = idx >> 2, d = idx & 3;
    if (d < 3) out[1 + 3 * i + d] = s;
}

extern "C" void kernel_launch(void* const* d_in, const int* in_sizes, int n_in,
                              void* d_out, int out_size, void* d_ws, size_t ws_size,
                              hipStream_t stream) {
    const float* pos  = (const float*)d_in[0];
    const float* cell = (const float*)d_in[1];
    const float* sigm = (const float*)d_in[2];
    const float* epsm = (const float*)d_in[3];
    const float* alpm = (const float*)d_in[4];
    const int*   spec = (const int*)d_in[5];
    float* out = (float*)d_out;
    const int n = in_sizes[5];  // species array length = N

    const int nchunks = (n + TJ - 1) / TJ;
    const size_t ws_needed = (size_t)nchunks * n * sizeof(float4);
    const bool use_ws = (d_ws != nullptr) && (ws_size >= ws_needed);

    if (use_ws) {
        // Forces are plain-stored by reduce_forces; only out[0] (energy
        // atomic accumulator) needs zeroing.
        (void)hipMemsetAsync(out, 0, sizeof(float), stream);
    } else {
        size_t logical = (size_t)(1 + 3 * n);
        if ((size_t)out_size < logical) logical = (size_t)out_size;
        (void)hipMemsetAsync(out, 0, logical * sizeof(float), stream);
    }

    dim3 grid(n / TI, nchunks);
    soft_sphere_kernel<<<grid, TI, 0, stream>>>(
        pos, cell, sigm, epsm, alpm, spec, out,
        use_ws ? (float4*)d_ws : nullptr, n);

    if (use_ws) {
        int total = 4 * n;
        int blocks = (total + 255) / 256;
        reduce_forces<<<blocks, 256, 0, stream>>>((const float*)d_ws, out,
                                                  n, nchunks);
    }
}

// Round 5
// 82.599 us; speedup vs baseline: 1.3370x; 1.1233x over previous
//
#include <hip/hip_runtime.h>

// Soft-sphere multi-species: energy + analytic forces. N=4096, S=8.
// O(N^2) tiled pair kernel. Grid: (N/TI) i-tiles x (N/TJ) j-chunks.
// Each thread owns particle i; j-chunk staged in LDS as float4 (xyz+species).
// Diagonal-cell fast path (uniform branch): per-axis minimum image.
// Per-pair tables {1/sig, alpha-1, eps/alpha, eps/sig} precomputed in LDS.
// f^(alpha-1) via hardware v_exp_f32/v_log_f32: f in (0,1].
//
// R3 evidence: force atomicAdds were 18.75 MB of RMW WRITE_SIZE at 440 GB/s
// == kernel time -> atomic-bound. R4 privatized forces into ws + reduce
// kernel: controllable slice 13-14 -> ~10 us (masked by +-2.5 us poison-fill
// noise; the two 256 MiB harness fills are ~80 us of dur_us, uncontrollable).
//
// R5: with atomics gone the R2 occupancy lever is live again:
//  - TJ 64->32: 8192 waves = 8/SIMD (was 4). Cost is only +4.2 MB plain
//    streaming writes now, not RMW. Unroll 8 + __launch_bounds__(256,8)
//    (pins VGPR<=64 so 8 waves/SIMD is reachable).
//  - Energy privatized per-block into ws tail; reduce kernel writes out[0]
//    -> zero atomics, memset dispatch deleted.
//  - Reduce: unroll 16 for MLP; +1 block reduces the 2048 energy partials.

#define TI 256
#define TJ 32
#define CUT2 2.25f  // CUTOFF=1.5 squared

__device__ __forceinline__ float fast_pow(float f, float e) {
    // f > 0 guaranteed. 2^(e * log2(f)) on the hardware transcendental pipe.
    return __builtin_amdgcn_exp2f(e * __builtin_amdgcn_logf(f));
}

__global__ __launch_bounds__(TI, 8) void soft_sphere_kernel(
    const float* __restrict__ pos,
    const float* __restrict__ cell,
    const float* __restrict__ sigm,
    const float* __restrict__ epsm,
    const float* __restrict__ alpm,
    const int*   __restrict__ spec,
    float*  __restrict__ out,   // fallback only: out[0]=energy, out[1..3N]=forces
    float4* __restrict__ ws,    // [nchunks][N] partial forces; null -> atomic path
    float*  __restrict__ ews,   // [nblocks] partial energies (ws tail)
    int n)
{
    __shared__ float4 sh_pos[TJ];   // j positions + species bits in .w
    __shared__ float4 sh_tab[64];   // {inv_sig, alpha-1, eps/alpha, eps/sig}
    __shared__ float  sh_e[TI / 64];

    const int tid = threadIdx.x;
    const int j0  = blockIdx.y * TJ;

    if (tid < 64) {
        // Species-pair coefficient tables (8x8 = 64 entries).
        float sg = sigm[tid], ep = epsm[tid], al = alpm[tid];
        float inv_sg = 1.0f / sg;
        sh_tab[tid] = make_float4(inv_sg, al - 1.0f, ep / al, ep * inv_sg);
        // j-chunk staging (TJ <= 64).
        if (tid < TJ) {
            int j = j0 + tid;
            sh_pos[tid] = make_float4(pos[3 * j + 0], pos[3 * j + 1],
                                      pos[3 * j + 2], __int_as_float(spec[j]));
        }
    }

    // Cell (uniform -> SGPRs).
    const float m00 = cell[0], m01 = cell[1], m02 = cell[2];
    const float m10 = cell[3], m11 = cell[4], m12 = cell[5];
    const float m20 = cell[6], m21 = cell[7], m22 = cell[8];
    const bool diag = (m01 == 0.0f) & (m02 == 0.0f) & (m10 == 0.0f) &
                      (m12 == 0.0f) & (m20 == 0.0f) & (m21 == 0.0f);

    const int   i   = blockIdx.x * TI + tid;
    const float px  = pos[3 * i + 0];
    const float py  = pos[3 * i + 1];
    const float pz  = pos[3 * i + 2];
    const int   si8 = spec[i] << 3;

    __syncthreads();

    float e_acc = 0.0f, fxa = 0.0f, fya = 0.0f, fza = 0.0f;

    if (diag) {
        // Orthorhombic fast path: per-axis minimum image.
        const float iLx = 1.0f / m00, iLy = 1.0f / m11, iLz = 1.0f / m22;
#pragma unroll 8
        for (int t = 0; t < TJ; ++t) {
            float4 pj = sh_pos[t];
            float dx = pj.x - px;
            float dy = pj.y - py;
            float dz = pj.z - pz;
            dx = fmaf(-rintf(dx * iLx), m00, dx);
            dy = fmaf(-rintf(dy * iLy), m11, dy);
            dz = fmaf(-rintf(dz * iLz), m22, dz);
            float r2 = fmaf(dx, dx, fmaf(dy, dy, dz * dz));
            if (r2 < CUT2 && (j0 + t) != i) {
                float4 tab = sh_tab[si8 + __float_as_int(pj.w)];
                float rinv = rsqrtf(r2);
                float r    = r2 * rinv;
                float f    = fmaf(-r, tab.x, 1.0f);   // 1 - r/sig
                if (f > 0.0f) {
                    float p = fast_pow(f, tab.y);        // f^(alpha-1)
                    e_acc = fmaf(tab.z * p, f, e_acc);   // eps/alpha * f^alpha
                    float c = tab.w * p * rinv;          // eps/(sig*r) * f^(a-1)
                    fxa = fmaf(-c, dx, fxa);
                    fya = fmaf(-c, dy, fya);
                    fza = fmaf(-c, dz, fza);
                }
            }
        }
    } else {
        // General triclinic path (never taken for this input, kept for correctness).
        const float det = m00 * (m11 * m22 - m12 * m21)
                        - m01 * (m10 * m22 - m12 * m20)
                        + m02 * (m10 * m21 - m11 * m20);
        const float rdet = 1.0f / det;
        const float i00 = (m11 * m22 - m12 * m21) * rdet;
        const float i01 = (m02 * m21 - m01 * m22) * rdet;
        const float i02 = (m01 * m12 - m02 * m11) * rdet;
        const float i10 = (m12 * m20 - m10 * m22) * rdet;
        const float i11 = (m00 * m22 - m02 * m20) * rdet;
        const float i12 = (m02 * m10 - m00 * m12) * rdet;
        const float i20 = (m10 * m21 - m11 * m20) * rdet;
        const float i21 = (m01 * m20 - m00 * m21) * rdet;
        const float i22 = (m00 * m11 - m01 * m10) * rdet;
#pragma unroll 2
        for (int t = 0; t < TJ; ++t) {
            float4 pj = sh_pos[t];
            float dx = pj.x - px, dy = pj.y - py, dz = pj.z - pz;
            float fx = dx * i00 + dy * i10 + dz * i20;
            float fy = dx * i01 + dy * i11 + dz * i21;
            float fz = dx * i02 + dy * i12 + dz * i22;
            fx -= rintf(fx); fy -= rintf(fy); fz -= rintf(fz);
            float ddx = fx * m00 + fy * m10 + fz * m20;
            float ddy = fx * m01 + fy * m11 + fz * m21;
            float ddz = fx * m02 + fy * m12 + fz * m22;
            float r2 = fmaf(ddx, ddx, fmaf(ddy, ddy, ddz * ddz));
            if (r2 < CUT2 && (j0 + t) != i) {
                float4 tab = sh_tab[si8 + __float_as_int(pj.w)];
                float rinv = rsqrtf(r2);
                float r    = r2 * rinv;
                float f    = fmaf(-r, tab.x, 1.0f);
                if (f > 0.0f) {
                    float p = fast_pow(f, tab.y);
                    e_acc = fmaf(tab.z * p, f, e_acc);
                    float c = tab.w * p * rinv;
                    fxa = fmaf(-c, ddx, fxa);
                    fya = fmaf(-c, ddy, fya);
                    fza = fmaf(-c, ddz, fza);
                }
            }
        }
    }

    // Force output: privatized plain store (no RMW traffic) when ws given.
    if (ws != nullptr) {
        ws[(size_t)blockIdx.y * n + i] = make_float4(fxa, fya, fza, 0.0f);
    } else {
        atomicAdd(&out[1 + 3 * i + 0], fxa);
        atomicAdd(&out[1 + 3 * i + 1], fya);
        atomicAdd(&out[1 + 3 * i + 2], fza);
    }

    // Energy: wave shuffle reduce -> LDS across waves -> one value per block.
    for (int off = 32; off > 0; off >>= 1)
        e_acc += __shfl_down(e_acc, off, 64);
    if ((tid & 63) == 0) sh_e[tid >> 6] = e_acc;
    __syncthreads();
    if (tid == 0) {
        float tot = 0.0f;
        for (int w = 0; w < TI / 64; ++w) tot += sh_e[w];
        float half = 0.5f * tot;  // ordered pairs counted twice
        if (ws != nullptr)
            ews[blockIdx.y * gridDim.x + blockIdx.x] = half;
        else
            atomicAdd(&out[0], half);
    }
}

// Sum per-chunk partial forces (blocks 0..FB-1) and per-block partial
// energies (last block). One thread per padded component; reads are
// lane-consecutive -> fully coalesced.
__global__ __launch_bounds__(256) void reduce_forces(
    const float* __restrict__ ws,   // [nchunks][n][4]
    const float* __restrict__ ews,  // [nblocks] energies
    float* __restrict__ out,        // out[0]=energy, out[1..3n]=forces
    int n, int nchunks, int nblocks)
{
    __shared__ float sh_e[4];
    const int tid = threadIdx.x;

    if ((int)blockIdx.x == gridDim.x - 1) {
        // Energy reduction block.
        float s = 0.0f;
        for (int k = tid; k < nblocks; k += 256) s += ews[k];
        for (int off = 32; off > 0; off >>= 1)
            s += __shfl_down(s, off, 64);
        if ((tid & 63) == 0) sh_e[tid >> 6] = s;
        __syncthreads();
        if (tid == 0)
            out[0] = sh_e[0] + sh_e[1] + sh_e[2] + sh_e[3];
        return;
    }

    const int idx = blockIdx.x * 256 + tid;   // [0, 4n)
    const int total = 4 * n;
    float s = 0.0f;
#pragma unroll 16
    for (int c = 0; c < nchunks; ++c)
        s += ws[(size_t)c * total + idx];
    const int i = idx >> 2, d = idx & 3;
    if (d < 3) out[1 + 3 * i + d] = s;
}

extern "C" void kernel_launch(void* const* d_in, const int* in_sizes, int n_in,
                              void* d_out, int out_size, void* d_ws, size_t ws_size,
                              hipStream_t stream) {
    const float* pos  = (const float*)d_in[0];
    const float* cell = (const float*)d_in[1];
    const float* sigm = (const float*)d_in[2];
    const float* epsm = (const float*)d_in[3];
    const float* alpm = (const float*)d_in[4];
    const int*   spec = (const int*)d_in[5];
    float* out = (float*)d_out;
    const int n = in_sizes[5];  // species array length = N

    const int nchunks  = (n + TJ - 1) / TJ;       // 128
    const int nblocks  = (n / TI) * nchunks;      // 2048
    const size_t fbytes = (size_t)nchunks * n * sizeof(float4);  // 8.4 MB
    const size_t ws_needed = fbytes + (size_t)nblocks * sizeof(float);
    const bool use_ws = (d_ws != nullptr) && (ws_size >= ws_needed);

    float4* fpart = use_ws ? (float4*)d_ws : nullptr;
    float*  epart = use_ws ? (float*)((char*)d_ws + fbytes) : nullptr;

    if (!use_ws) {
        // Fallback: atomic accumulation needs zeroed outputs.
        size_t logical = (size_t)(1 + 3 * n);
        if ((size_t)out_size < logical) logical = (size_t)out_size;
        (void)hipMemsetAsync(out, 0, logical * sizeof(float), stream);
    }

    dim3 grid(n / TI, nchunks);
    soft_sphere_kernel<<<grid, TI, 0, stream>>>(
        pos, cell, sigm, epsm, alpm, spec, out, fpart, epart, n);

    if (use_ws) {
        int fb = (4 * n + 255) / 256;             // 64 force blocks
        reduce_forces<<<fb + 1, 256, 0, stream>>>(
            (const float*)d_ws, epart, out, n, nchunks, nblocks);
    }
}